// Round 8
// baseline (400.817 us; speedup 1.0000x reference)
//
#include <hip/hip_runtime.h>
#include <hip/hip_bf16.h>

#define SPAT 32768   // 32*32*32
#define BATCH 2
#define GN_EPS 1e-5f

__device__ __forceinline__ void fma4(float4& a, const float4& v, float w) {
    a.x = fmaf(v.x, w, a.x); a.y = fmaf(v.y, w, a.y);
    a.z = fmaf(v.z, w, a.z); a.w = fmaf(v.w, w, a.w);
}

// ---------------- 1x1x1 conv: float4 spatial x 4 output channels ----------------
// grid: (SPAT/1024, Cout/4, B), block 256  -> cv1/cv3: 512 blocks
template <bool RELU, bool AFF>
__global__ __launch_bounds__(256) void k_c1(
    const float* __restrict__ in, const float* __restrict__ w,
    const float* __restrict__ sc, const float* __restrict__ bi,
    float* __restrict__ out, int Cin, int Cout)
{
    int q = blockIdx.x * 256 + threadIdx.x;
    int s = q * 4;
    int o0 = blockIdx.y * 4, b = blockIdx.z;
    const float* ip = in + (size_t)b * Cin * SPAT + s;
    float4 a0 = {0,0,0,0}, a1 = a0, a2 = a0, a3 = a0;
#pragma unroll 4
    for (int c = 0; c < Cin; ++c) {
        float4 v = *(const float4*)(ip + (size_t)c * SPAT);
        fma4(a0, v, w[(o0+0)*Cin + c]);
        fma4(a1, v, w[(o0+1)*Cin + c]);
        fma4(a2, v, w[(o0+2)*Cin + c]);
        fma4(a3, v, w[(o0+3)*Cin + c]);
    }
    float4 accs[4] = {a0, a1, a2, a3};
#pragma unroll
    for (int i = 0; i < 4; ++i) {
        int o = o0 + i;
        float scale = AFF ? sc[o] : 1.f;
        float shift = bi[o];
        float4 r = accs[i];
        r.x = r.x * scale + shift; r.y = r.y * scale + shift;
        r.z = r.z * scale + shift; r.w = r.w * scale + shift;
        if (RELU) {
            r.x = fmaxf(r.x, 0.f); r.y = fmaxf(r.y, 0.f);
            r.z = fmaxf(r.z, 0.f); r.w = fmaxf(r.w, 0.f);
        }
        *(float4*)(out + ((size_t)b * Cout + o) * SPAT + s) = r;
    }
}

// Decode XCD-aware swizzled 1D block id (kept for cv4).
template <int OG>
__device__ __forceinline__ void decode_swz(int bid, int& og, int& b, int& s) {
    int xcd = bid & 7;
    int rest = bid >> 3;
    og = rest % OG;
    int pair = rest / OG;            // 0..7
    int spb = pair * 8 + xcd;        // 0..63
    b = spb >> 5;
    s = (spb & 31) * 1024 + threadIdx.x * 4;
}

// ---------------- cv4 (32->216) + bias + fused GN partial stats ----------------
__global__ __launch_bounds__(256) void k_cv4(
    const float* __restrict__ in, const float* __restrict__ w,
    const float* __restrict__ bi, float* __restrict__ out,
    float* __restrict__ partial)
{
    int og, b, s;
    decode_swz<27>(blockIdx.x, og, b, s);
    int sp = s >> 10;
    int o0 = og * 8;
    const float* ip = in + (size_t)b * 32 * SPAT + s;
    float4 acc[8];
#pragma unroll
    for (int i = 0; i < 8; ++i) acc[i] = {0, 0, 0, 0};
#pragma unroll 4
    for (int c = 0; c < 32; ++c) {
        float4 v = *(const float4*)(ip + (size_t)c * SPAT);
#pragma unroll
        for (int i = 0; i < 8; ++i)
            fma4(acc[i], v, w[(o0 + i) * 32 + c]);
    }
    float sums[8], sss[8];
#pragma unroll
    for (int i = 0; i < 8; ++i) {
        int o = o0 + i;
        float shift = bi[o];
        float4 r = acc[i];
        r.x += shift; r.y += shift; r.z += shift; r.w += shift;
        *(float4*)(out + ((size_t)b * 216 + o) * SPAT + s) = r;
        sums[i] = r.x + r.y + r.z + r.w;
        sss[i]  = r.x * r.x + r.y * r.y + r.z * r.z + r.w * r.w;
    }
#pragma unroll
    for (int off = 32; off > 0; off >>= 1) {
#pragma unroll
        for (int i = 0; i < 8; ++i) {
            sums[i] += __shfl_down(sums[i], off, 64);
            sss[i]  += __shfl_down(sss[i],  off, 64);
        }
    }
    __shared__ float sh[4][8][2];
    int wave = threadIdx.x >> 6, lane = threadIdx.x & 63;
    if (lane == 0) {
#pragma unroll
        for (int i = 0; i < 8; ++i) {
            sh[wave][i][0] = sums[i];
            sh[wave][i][1] = sss[i];
        }
    }
    __syncthreads();
    if (threadIdx.x < 8) {
        int i = threadIdx.x;
        float s0 = sh[0][i][0] + sh[1][i][0] + sh[2][i][0] + sh[3][i][0];
        float s1 = sh[0][i][1] + sh[1][i][1] + sh[2][i][1] + sh[3][i][1];
        int o = o0 + i;
        int idx = ((b * 216 + o) * 32 + sp) * 2;
        partial[idx + 0] = s0;
        partial[idx + 1] = s1;
    }
}

// ---------------- GN stats stage 2 ----------------
__global__ __launch_bounds__(256) void k_gn_stats2(
    const float* __restrict__ partial, float* __restrict__ stats)
{
    int bg = blockIdx.x;
    int b = bg >> 3, g = bg & 7;
    float sum = 0.f, ss = 0.f;
    for (int i = threadIdx.x; i < 27 * 32; i += 256) {
        int o = g * 27 + (i >> 5);
        int xb = i & 31;
        int idx = ((b * 216 + o) * 32 + xb) * 2;
        sum += partial[idx + 0];
        ss  += partial[idx + 1];
    }
    __shared__ float sh[512];
    sh[threadIdx.x] = sum; sh[256 + threadIdx.x] = ss;
    __syncthreads();
    for (int off = 128; off > 0; off >>= 1) {
        if (threadIdx.x < off) {
            sh[threadIdx.x] += sh[threadIdx.x + off];
            sh[256 + threadIdx.x] += sh[256 + threadIdx.x + off];
        }
        __syncthreads();
    }
    if (threadIdx.x == 0) {
        stats[bg * 2 + 0] = sh[0];
        stats[bg * 2 + 1] = sh[256];
    }
}

// ---------------- depthwise 5x5x5, zero pad 2, + affine, LDS-tiled ----------------
__global__ __launch_bounds__(256) void k_dw5(
    const float* __restrict__ in, const float* __restrict__ w2,
    const float* __restrict__ s2, const float* __restrict__ b2,
    float* __restrict__ out)
{
    __shared__ float lds[8 * 36 * 40];           // 46,080 B
    int tid = threadIdx.x;
    int d0 = blockIdx.x * 4;
    int c = blockIdx.y, b = blockIdx.z;
    const float* ip = in + ((size_t)(b * 32 + c)) * SPAT;

    float4 z = {0, 0, 0, 0};
    for (int i = tid; i < 8 * 36 * 40 / 4; i += 256)
        ((float4*)lds)[i] = z;
    __syncthreads();
    for (int i = tid; i < 8 * 256; i += 256) {
        int p = i >> 8, rem = i & 255;
        int r = rem >> 3, c4 = (rem & 7) * 4;
        int d = d0 - 2 + p;
        if (d >= 0 && d < 32) {
            float4 v = *(const float4*)(ip + d * 1024 + r * 32 + c4);
            *(float4*)&lds[p * 1440 + (r + 2) * 40 + (c4 + 4)] = v;
        }
    }
    __syncthreads();

    float scl = s2[c], shf = b2[c];
    const float* wt = w2 + c * 125;
#pragma unroll
    for (int k = 0; k < 4; ++k) {
        int j = tid + k * 256;
        int pd = j >> 8, rem = j & 255;
        int hr = rem >> 3, w4 = (rem & 7) * 4;
        float4 acc = {0, 0, 0, 0};
#pragma unroll
        for (int kd = 0; kd < 5; ++kd) {
            const float* pl = &lds[(pd + kd) * 1440];
#pragma unroll
            for (int kh = 0; kh < 5; ++kh) {
                const float* row = pl + (hr + kh) * 40 + w4;
                float4 r0 = *(const float4*)(row);
                float4 r1 = *(const float4*)(row + 4);
                float4 r2 = *(const float4*)(row + 8);
                float win[12] = {r0.x, r0.y, r0.z, r0.w,
                                 r1.x, r1.y, r1.z, r1.w,
                                 r2.x, r2.y, r2.z, r2.w};
#pragma unroll
                for (int kw = 0; kw < 5; ++kw) {
                    float wv = wt[kd * 25 + kh * 5 + kw];
                    acc.x = fmaf(wv, win[2 + 0 + kw], acc.x);
                    acc.y = fmaf(wv, win[2 + 1 + kw], acc.y);
                    acc.z = fmaf(wv, win[2 + 2 + kw], acc.z);
                    acc.w = fmaf(wv, win[2 + 3 + kw], acc.w);
                }
            }
        }
        acc.x = acc.x * scl + shf; acc.y = acc.y * scl + shf;
        acc.z = acc.z * scl + shf; acc.w = acc.w * scl + shf;
        *(float4*)(out + ((size_t)(b * 32 + c)) * SPAT
                   + (d0 + pd) * 1024 + hr * 32 + w4) = acc;
    }
}

// ---------------- fused SKA + BN + residual + FFN -> out ----------------
// grid: 256 blocks = BATCH * (SPAT/256) chunks, block 256.
// Phase A: SKA (8 groups x 64 quads, 2 quads/thread) -> y in LDS (swizzled).
// Phase B: 1 thread = 1 position: f[128] tiles in regs, out stored directly.
__global__ __launch_bounds__(256) void k_ska_ffn(
    const float* __restrict__ x, const float* __restrict__ wk,
    const float* __restrict__ stats,
    const float* __restrict__ gn_g, const float* __restrict__ gn_b,
    const float* __restrict__ bn_s, const float* __restrict__ bn_b,
    const float* __restrict__ w1, const float* __restrict__ s1f,
    const float* __restrict__ b1f,
    const float* __restrict__ w2, const float* __restrict__ s2f,
    const float* __restrict__ b2f,
    float* __restrict__ out)
{
    __shared__ float yl[256 * 64];               // 64 KB; yl[p*64 + ((c+p)&63)]
    int tid = threadIdx.x;
    int cid = blockIdx.x;
    int b = cid >> 7;                            // 128 chunks per batch
    int s0 = (cid & 127) * 256;                  // chunk start, < SPAT
    int d0 = s0 >> 10;
    int h0 = (s0 >> 5) & 31;

    // ---- phase A: SKA ----
    int g = tid >> 5, u = tid & 31;
    int lane = tid & 63;
    int xl_src = (lane & 56) | ((lane + 7) & 7);
    int xr_src = (lane & 56) | ((lane + 1) & 7);
    int bg = b * 8 + g;
    const float N = 27.f * (float)SPAT;
    float mu  = stats[bg * 2 + 0] / N;
    float var = stats[bg * 2 + 1] / N - mu * mu;
    float inv = rsqrtf(var + GN_EPS);
    const float* xg  = x + ((size_t)(b * 64 + g * 8)) * SPAT;
    const float* wpb = wk + ((size_t)(b * 216 + g * 27)) * SPAT;

#pragma unroll
    for (int pass = 0; pass < 2; ++pass) {
        int q = u + pass * 32;                   // quad 0..63 in chunk
        int h = h0 + (q >> 3);
        int w0 = (q & 7) * 4;
        int sq = s0 + q * 4;                     // global spatial index
        const float* wp = wpb + sq;

        float4 acc[8];
        float4 xc[8];
#pragma unroll
        for (int c = 0; c < 8; ++c) acc[c] = {0, 0, 0, 0};

#pragma unroll
        for (int kd = 0; kd < 3; ++kd) {
            int zd = (d0 + kd + 31) & 31;
#pragma unroll
            for (int kh = 0; kh < 3; ++kh) {
                int zh = (h + kh + 31) & 31;
                int kbase = (kd * 3 + kh) * 3;
                float wn[3][4];
#pragma unroll
                for (int kw = 0; kw < 3; ++kw) {
                    int kk = kbase + kw;
                    float4 wq = *(const float4*)(wp + (size_t)kk * SPAT);
                    float gg = gn_g[g * 27 + kk], gb = gn_b[g * 27 + kk];
                    wn[kw][0] = (wq.x - mu) * inv * gg + gb;
                    wn[kw][1] = (wq.y - mu) * inv * gg + gb;
                    wn[kw][2] = (wq.z - mu) * inv * gg + gb;
                    wn[kw][3] = (wq.w - mu) * inv * gg + gb;
                }
                int rowoff = zd * 1024 + zh * 32;
                bool center = (kd == 1) && (kh == 1);
#pragma unroll
                for (int c = 0; c < 8; ++c) {
                    float4 m = *(const float4*)(xg + (size_t)c * SPAT + rowoff + w0);
                    if (center) xc[c] = m;
                    float xl = __shfl(m.w, xl_src, 64);
                    float xr = __shfl(m.x, xr_src, 64);
                    float win[6] = {xl, m.x, m.y, m.z, m.w, xr};
#pragma unroll
                    for (int kw = 0; kw < 3; ++kw) {
                        acc[c].x = fmaf(win[0 + kw], wn[kw][0], acc[c].x);
                        acc[c].y = fmaf(win[1 + kw], wn[kw][1], acc[c].y);
                        acc[c].z = fmaf(win[2 + kw], wn[kw][2], acc[c].z);
                        acc[c].w = fmaf(win[3 + kw], wn[kw][3], acc[c].w);
                    }
                }
            }
        }
        // y = ska*bn_s + bn_b + x  -> LDS (swizzled)
#pragma unroll
        for (int c = 0; c < 8; ++c) {
            int ch = g * 8 + c;
            float bs = bn_s[ch], bb = bn_b[ch];
            float4 r;
            r.x = acc[c].x * bs + bb + xc[c].x;
            r.y = acc[c].y * bs + bb + xc[c].y;
            r.z = acc[c].z * bs + bb + xc[c].z;
            r.w = acc[c].w * bs + bb + xc[c].w;
            int p0 = q * 4;
            yl[(p0 + 0) * 64 + ((ch + p0 + 0) & 63)] = r.x;
            yl[(p0 + 1) * 64 + ((ch + p0 + 1) & 63)] = r.y;
            yl[(p0 + 2) * 64 + ((ch + p0 + 2) & 63)] = r.z;
            yl[(p0 + 3) * 64 + ((ch + p0 + 3) & 63)] = r.w;
        }
    }
    __syncthreads();

    // ---- phase B: FFN, 1 thread = 1 position ----
    int p = tid;
    float yv[64];
#pragma unroll
    for (int c = 0; c < 64; ++c) yv[c] = yl[p * 64 + ((c + p) & 63)];

    float outacc[64];
#pragma unroll
    for (int o = 0; o < 64; ++o) outacc[o] = 0.f;

    for (int t = 0; t < 8; ++t) {                // 8 tiles of 16 f-channels
        int j0 = t * 16;
        float f[16];
#pragma unroll
        for (int jj = 0; jj < 16; ++jj) {
            int j = j0 + jj;
            const float* wr = w1 + j * 64;       // wave-uniform -> s_load
            float a = 0.f;
#pragma unroll
            for (int c = 0; c < 64; ++c) a = fmaf(wr[c], yv[c], a);
            a = a * s1f[j] + b1f[j];
            f[jj] = fmaxf(a, 0.f);
        }
#pragma unroll
        for (int o = 0; o < 64; ++o) {
            const float* w2r = w2 + o * 128 + j0;
            float a = outacc[o];
#pragma unroll
            for (int jj = 0; jj < 16; ++jj) a = fmaf(w2r[jj], f[jj], a);
            outacc[o] = a;
        }
    }
    float* op = out + (size_t)b * 64 * SPAT + s0 + p;
#pragma unroll
    for (int o = 0; o < 64; ++o) {
        float r = outacc[o] * s2f[o] + b2f[o] + yl[p * 64 + ((o + p) & 63)];
        op[(size_t)o * SPAT] = r;
    }
}

extern "C" void kernel_launch(void* const* d_in, const int* in_sizes, int n_in,
                              void* d_out, int out_size, void* d_ws, size_t ws_size,
                              hipStream_t stream)
{
    const float* x     = (const float*)d_in[0];
    const float* w1    = (const float*)d_in[1];
    const float* s1    = (const float*)d_in[2];
    const float* b1    = (const float*)d_in[3];
    const float* w2    = (const float*)d_in[4];
    const float* s2    = (const float*)d_in[5];
    const float* b2    = (const float*)d_in[6];
    const float* w3    = (const float*)d_in[7];
    const float* s3    = (const float*)d_in[8];
    const float* b3    = (const float*)d_in[9];
    const float* w4    = (const float*)d_in[10];
    const float* b4    = (const float*)d_in[11];
    const float* gn_g  = (const float*)d_in[12];
    const float* gn_b  = (const float*)d_in[13];
    const float* bn_s  = (const float*)d_in[14];
    const float* bn_b  = (const float*)d_in[15];
    const float* pw1_w = (const float*)d_in[16];
    const float* pw1_s = (const float*)d_in[17];
    const float* pw1_b = (const float*)d_in[18];
    const float* pw2_w = (const float*)d_in[19];
    const float* pw2_s = (const float*)d_in[20];
    const float* pw2_b = (const float*)d_in[21];

    // Workspace (~73.7 MB): a1 | a2 | wk | part | stats   (y/f1 eliminated)
    float* ws    = (float*)d_ws;
    float* a1    = ws;                                   // 2*32*S
    float* a2    = a1 + (size_t)BATCH * 32 * SPAT;       // 2*32*S
    float* wkb   = a2 + (size_t)BATCH * 32 * SPAT;       // 2*216*S
    float* part  = wkb + (size_t)BATCH * 216 * SPAT;     // 2*216*32*2
    float* stats = part + BATCH * 216 * 32 * 2;          // 32

    dim3 blk(256);
    // cv1 + BN + ReLU : 64 -> 32  (512 blocks)
    k_c1<true, true><<<dim3(SPAT / 1024, 8, BATCH), blk, 0, stream>>>(
        x, w1, s1, b1, a1, 64, 32);
    // dw 5^3 + BN (LDS-tiled)
    k_dw5<<<dim3(8, 32, BATCH), blk, 0, stream>>>(a1, w2, s2, b2, a2);
    // cv3 + BN + ReLU : 32 -> 32  (512 blocks)
    k_c1<true, true><<<dim3(SPAT / 1024, 8, BATCH), blk, 0, stream>>>(
        a2, w3, s3, b3, a1, 32, 32);
    // cv4 + bias + fused GN partial stats : 32 -> 216
    k_cv4<<<dim3(27 * 64), blk, 0, stream>>>(a1, w4, b4, wkb, part);
    // GN stats stage 2
    k_gn_stats2<<<dim3(16), blk, 0, stream>>>(part, stats);
    // fused SKA + BN + residual + FFN -> out  (BATCH * SPAT/256 = 256 blocks)
    k_ska_ffn<<<dim3(BATCH * (SPAT / 256)), blk, 0, stream>>>(
        x, wkb, stats, gn_g, gn_b, bn_s, bn_b,
        pw1_w, pw1_s, pw1_b, pw2_w, pw2_s, pw2_b, (float*)d_out);
}

// Round 9
// 232.732 us; speedup vs baseline: 1.7222x; 1.7222x over previous
//
#include <hip/hip_runtime.h>
#include <hip/hip_bf16.h>

#define SPAT 32768   // 32*32*32
#define BATCH 2
#define GN_EPS 1e-5f
#define CPAD 224     // cv4 padded output channels (216 -> 224)

typedef __attribute__((ext_vector_type(8))) short bf16x8;
typedef __attribute__((ext_vector_type(4))) float f32x4;

__device__ __forceinline__ short f2bf(float f) {
    __hip_bfloat16 h = __float2bfloat16(f);
    return *reinterpret_cast<short*>(&h);
}

// ============ MFMA pointwise conv ============
// out[o][s] = act(affine(sum_c w[o][c] * in[c][s]))  via 16x16x32 bf16 MFMA.
// M=spatial (128/block), N=o (COUT padded to x16), K=c.
// Block 256 (4 waves x 2 m-tiles of 16). grid (SPAT/128, 1, BATCH).
// A[m=lane&15][k=quad*8+j], B[k=quad*8+j][n=lane&15], D[m=quad*4+r][n=lane&15].
template <int CIN, int COUT, int COUT_REAL, bool RELU, bool AFF, bool STATS, bool RES>
__global__ __launch_bounds__(256) void k_mfma_pw(
    const float* __restrict__ in, const float* __restrict__ w,
    const float* __restrict__ sc, const float* __restrict__ bi,
    const float* __restrict__ yres,
    float* __restrict__ out, float* __restrict__ partial)
{
    constexpr int LT = CIN + 8;          // LDS row stride (shorts), 16B-aligned
    constexpr int KS = CIN / 32;
    constexpr int NT = COUT / 16;
    __shared__ short lt[128 * LT];       // activation tile [p][c] bf16
    __shared__ short wt[COUT * LT];      // weights [o][c] bf16
    int tid = threadIdx.x;
    int b = blockIdx.z;
    int s0 = blockIdx.x * 128;

    // ---- stage activations (coalesced global, scatter LDS) ----
    const float* ip = in + (size_t)b * CIN * SPAT + s0;
#pragma unroll
    for (int it = 0; it < CIN / 8; ++it) {
        int j = tid + it * 256;
        int c = j >> 5;                  // 32 quads of positions per channel
        int p4 = (j & 31) * 4;
        float4 v = *(const float4*)(ip + (size_t)c * SPAT + p4);
        lt[(p4 + 0) * LT + c] = f2bf(v.x);
        lt[(p4 + 1) * LT + c] = f2bf(v.y);
        lt[(p4 + 2) * LT + c] = f2bf(v.z);
        lt[(p4 + 3) * LT + c] = f2bf(v.w);
    }
    // ---- stage weights ----
#pragma unroll
    for (int it = 0; it < COUT * CIN / 256; ++it) {
        int j = tid + it * 256;
        int o = j / CIN, c = j % CIN;
        float wv = (COUT == COUT_REAL || o < COUT_REAL) ? w[o * CIN + c] : 0.f;
        wt[o * LT + c] = f2bf(wv);
    }
    __syncthreads();

    int wave = tid >> 6, lane = tid & 63, quad = lane >> 4, l15 = lane & 15;
    int wp0 = wave * 32;                 // 2 m-tiles per wave

    bf16x8 afr[2][KS];
#pragma unroll
    for (int m = 0; m < 2; ++m) {
        int p = wp0 + m * 16 + l15;
#pragma unroll
        for (int kk = 0; kk < KS; ++kk)
            afr[m][kk] = *(const bf16x8*)&lt[p * LT + kk * 32 + quad * 8];
    }

    for (int nt = 0; nt < NT; ++nt) {
        int o = nt * 16 + l15;
        bf16x8 bfr[KS];
#pragma unroll
        for (int kk = 0; kk < KS; ++kk)
            bfr[kk] = *(const bf16x8*)&wt[o * LT + kk * 32 + quad * 8];
        f32x4 acc[2] = {{0.f, 0.f, 0.f, 0.f}, {0.f, 0.f, 0.f, 0.f}};
#pragma unroll
        for (int kk = 0; kk < KS; ++kk) {
            acc[0] = __builtin_amdgcn_mfma_f32_16x16x32_bf16(afr[0][kk], bfr[kk], acc[0], 0, 0, 0);
            acc[1] = __builtin_amdgcn_mfma_f32_16x16x32_bf16(afr[1][kk], bfr[kk], acc[1], 0, 0, 0);
        }
        float scale = AFF ? sc[o] : 1.f;
        float shift = (COUT == COUT_REAL || o < COUT_REAL) ? bi[o] : 0.f;
        float psum = 0.f, pss = 0.f;
#pragma unroll
        for (int m = 0; m < 2; ++m) {
            int pos = s0 + wp0 + m * 16 + quad * 4;
            float4 r;
            r.x = acc[m][0] * scale + shift;
            r.y = acc[m][1] * scale + shift;
            r.z = acc[m][2] * scale + shift;
            r.w = acc[m][3] * scale + shift;
            if (RELU) {
                r.x = fmaxf(r.x, 0.f); r.y = fmaxf(r.y, 0.f);
                r.z = fmaxf(r.z, 0.f); r.w = fmaxf(r.w, 0.f);
            }
            if (RES) {
                float4 yv = *(const float4*)(yres + ((size_t)(b * COUT + o)) * SPAT + pos);
                r.x += yv.x; r.y += yv.y; r.z += yv.z; r.w += yv.w;
            }
            *(float4*)(out + ((size_t)b * COUT + o) * SPAT + pos) = r;
            if (STATS) {
                psum += r.x + r.y + r.z + r.w;
                pss  += r.x * r.x + r.y * r.y + r.z * r.z + r.w * r.w;
            }
        }
        if (STATS) {
            // reduce across the 4 quads (same o)
            psum += __shfl_xor(psum, 16, 64); pss += __shfl_xor(pss, 16, 64);
            psum += __shfl_xor(psum, 32, 64); pss += __shfl_xor(pss, 32, 64);
            if (quad == 0) {
                int chunk = blockIdx.x * 4 + wave;         // 0..1023
                int idx = (((b * COUT + o) << 10) + chunk) * 2;
                partial[idx + 0] = psum;
                partial[idx + 1] = pss;
            }
        }
    }
}

// ============ GN stats stage 2: reduce 27 o x 1024 chunks per (b,g) ============
__global__ __launch_bounds__(256) void k_gn_stats2(
    const float* __restrict__ partial, float* __restrict__ stats)
{
    int bg = blockIdx.x;
    int b = bg >> 3, g = bg & 7;
    float sum = 0.f, ss = 0.f;
    for (int i = threadIdx.x; i < 27 * 1024; i += 256) {
        int o = g * 27 + (i >> 10);
        int ch = i & 1023;
        int idx = (((b * CPAD + o) << 10) + ch) * 2;
        sum += partial[idx + 0];
        ss  += partial[idx + 1];
    }
    __shared__ float sh[512];
    sh[threadIdx.x] = sum; sh[256 + threadIdx.x] = ss;
    __syncthreads();
    for (int off = 128; off > 0; off >>= 1) {
        if (threadIdx.x < off) {
            sh[threadIdx.x] += sh[threadIdx.x + off];
            sh[256 + threadIdx.x] += sh[256 + threadIdx.x + off];
        }
        __syncthreads();
    }
    if (threadIdx.x == 0) {
        stats[bg * 2 + 0] = sh[0];
        stats[bg * 2 + 1] = sh[256];
    }
}

// ============ depthwise 5x5x5, zero pad 2, + affine, LDS-tiled ============
__global__ __launch_bounds__(256) void k_dw5(
    const float* __restrict__ in, const float* __restrict__ w2,
    const float* __restrict__ s2, const float* __restrict__ b2,
    float* __restrict__ out)
{
    __shared__ float lds[8 * 36 * 40];
    int tid = threadIdx.x;
    int d0 = blockIdx.x * 4;
    int c = blockIdx.y, b = blockIdx.z;
    const float* ip = in + ((size_t)(b * 32 + c)) * SPAT;

    float4 z = {0, 0, 0, 0};
    for (int i = tid; i < 8 * 36 * 40 / 4; i += 256)
        ((float4*)lds)[i] = z;
    __syncthreads();
    for (int i = tid; i < 8 * 256; i += 256) {
        int p = i >> 8, rem = i & 255;
        int r = rem >> 3, c4 = (rem & 7) * 4;
        int d = d0 - 2 + p;
        if (d >= 0 && d < 32) {
            float4 v = *(const float4*)(ip + d * 1024 + r * 32 + c4);
            *(float4*)&lds[p * 1440 + (r + 2) * 40 + (c4 + 4)] = v;
        }
    }
    __syncthreads();

    float scl = s2[c], shf = b2[c];
    const float* wt = w2 + c * 125;
#pragma unroll
    for (int k = 0; k < 4; ++k) {
        int j = tid + k * 256;
        int pd = j >> 8, rem = j & 255;
        int hr = rem >> 3, w4 = (rem & 7) * 4;
        float4 acc = {0, 0, 0, 0};
#pragma unroll
        for (int kd = 0; kd < 5; ++kd) {
            const float* pl = &lds[(pd + kd) * 1440];
#pragma unroll
            for (int kh = 0; kh < 5; ++kh) {
                const float* row = pl + (hr + kh) * 40 + w4;
                float4 r0 = *(const float4*)(row);
                float4 r1 = *(const float4*)(row + 4);
                float4 r2 = *(const float4*)(row + 8);
                float win[12] = {r0.x, r0.y, r0.z, r0.w,
                                 r1.x, r1.y, r1.z, r1.w,
                                 r2.x, r2.y, r2.z, r2.w};
#pragma unroll
                for (int kw = 0; kw < 5; ++kw) {
                    float wv = wt[kd * 25 + kh * 5 + kw];
                    acc.x = fmaf(wv, win[2 + 0 + kw], acc.x);
                    acc.y = fmaf(wv, win[2 + 1 + kw], acc.y);
                    acc.z = fmaf(wv, win[2 + 2 + kw], acc.z);
                    acc.w = fmaf(wv, win[2 + 3 + kw], acc.w);
                }
            }
        }
        acc.x = acc.x * scl + shf; acc.y = acc.y * scl + shf;
        acc.z = acc.z * scl + shf; acc.w = acc.w * scl + shf;
        *(float4*)(out + ((size_t)(b * 32 + c)) * SPAT
                   + (d0 + pd) * 1024 + hr * 32 + w4) = acc;
    }
}

// ============ SKA (round-5 proven; wk stride CPAD) ============
__global__ __launch_bounds__(256) void k_ska(
    const float* __restrict__ x, const float* __restrict__ wk,
    const float* __restrict__ stats,
    const float* __restrict__ gn_g, const float* __restrict__ gn_b,
    const float* __restrict__ bn_s, const float* __restrict__ bn_b,
    float* __restrict__ y)
{
    int q = blockIdx.x * 256 + threadIdx.x;
    int s = q * 4;
    int g = blockIdx.y, b = blockIdx.z;
    int bg = b * 8 + g;
    const float N = 27.f * (float)SPAT;
    float mu  = stats[bg * 2 + 0] / N;
    float var = stats[bg * 2 + 1] / N - mu * mu;
    float inv = rsqrtf(var + GN_EPS);
    int d = s >> 10, h = (s >> 5) & 31, w0 = s & 31;
    int lane = threadIdx.x & 63;
    int xl_src = (lane & 56) | ((lane + 7) & 7);
    int xr_src = (lane & 56) | ((lane + 1) & 7);
    const float* xg = x + ((size_t)(b * 64 + g * 8)) * SPAT;
    const float* wp = wk + ((size_t)(b * CPAD + g * 27)) * SPAT + s;

    float4 acc[8];
    float4 xc[8];
#pragma unroll
    for (int c = 0; c < 8; ++c) acc[c] = {0, 0, 0, 0};

#pragma unroll
    for (int kd = 0; kd < 3; ++kd) {
        int zd = (d + kd + 31) & 31;
#pragma unroll
        for (int kh = 0; kh < 3; ++kh) {
            int zh = (h + kh + 31) & 31;
            int kbase = (kd * 3 + kh) * 3;
            float wn[3][4];
#pragma unroll
            for (int kw = 0; kw < 3; ++kw) {
                int kk = kbase + kw;
                float4 wq = *(const float4*)(wp + (size_t)kk * SPAT);
                float gg = gn_g[g * 27 + kk], gb = gn_b[g * 27 + kk];
                wn[kw][0] = (wq.x - mu) * inv * gg + gb;
                wn[kw][1] = (wq.y - mu) * inv * gg + gb;
                wn[kw][2] = (wq.z - mu) * inv * gg + gb;
                wn[kw][3] = (wq.w - mu) * inv * gg + gb;
            }
            int rowoff = zd * 1024 + zh * 32;
            bool center = (kd == 1) && (kh == 1);
#pragma unroll
            for (int c = 0; c < 8; ++c) {
                float4 m = *(const float4*)(xg + (size_t)c * SPAT + rowoff + w0);
                if (center) xc[c] = m;
                float xl = __shfl(m.w, xl_src, 64);
                float xr = __shfl(m.x, xr_src, 64);
                float win[6] = {xl, m.x, m.y, m.z, m.w, xr};
#pragma unroll
                for (int kw = 0; kw < 3; ++kw) {
                    acc[c].x = fmaf(win[0 + kw], wn[kw][0], acc[c].x);
                    acc[c].y = fmaf(win[1 + kw], wn[kw][1], acc[c].y);
                    acc[c].z = fmaf(win[2 + kw], wn[kw][2], acc[c].z);
                    acc[c].w = fmaf(win[3 + kw], wn[kw][3], acc[c].w);
                }
            }
        }
    }
#pragma unroll
    for (int c = 0; c < 8; ++c) {
        int ch = g * 8 + c;
        float bs = bn_s[ch], bb = bn_b[ch];
        float4 r;
        r.x = acc[c].x * bs + bb + xc[c].x;
        r.y = acc[c].y * bs + bb + xc[c].y;
        r.z = acc[c].z * bs + bb + xc[c].z;
        r.w = acc[c].w * bs + bb + xc[c].w;
        *(float4*)(y + ((size_t)(b * 64 + ch)) * SPAT + s) = r;
    }
}

extern "C" void kernel_launch(void* const* d_in, const int* in_sizes, int n_in,
                              void* d_out, int out_size, void* d_ws, size_t ws_size,
                              hipStream_t stream)
{
    const float* x     = (const float*)d_in[0];
    const float* w1    = (const float*)d_in[1];
    const float* s1    = (const float*)d_in[2];
    const float* b1    = (const float*)d_in[3];
    const float* w2    = (const float*)d_in[4];
    const float* s2    = (const float*)d_in[5];
    const float* b2    = (const float*)d_in[6];
    const float* w3    = (const float*)d_in[7];
    const float* s3    = (const float*)d_in[8];
    const float* b3    = (const float*)d_in[9];
    const float* w4    = (const float*)d_in[10];
    const float* b4    = (const float*)d_in[11];
    const float* gn_g  = (const float*)d_in[12];
    const float* gn_b  = (const float*)d_in[13];
    const float* bn_s  = (const float*)d_in[14];
    const float* bn_b  = (const float*)d_in[15];
    const float* pw1_w = (const float*)d_in[16];
    const float* pw1_s = (const float*)d_in[17];
    const float* pw1_b = (const float*)d_in[18];
    const float* pw2_w = (const float*)d_in[19];
    const float* pw2_s = (const float*)d_in[20];
    const float* pw2_b = (const float*)d_in[21];

    // ws: a1 | a2 | yb | wk(224 rows) | f1 | part | stats  (~134 MB)
    float* ws    = (float*)d_ws;
    float* a1    = ws;                                    // 2*32*S
    float* a2    = a1 + (size_t)BATCH * 32 * SPAT;        // 2*32*S
    float* yb    = a2 + (size_t)BATCH * 32 * SPAT;        // 2*64*S
    float* wkb   = yb + (size_t)BATCH * 64 * SPAT;        // 2*224*S
    float* f1    = wkb + (size_t)BATCH * CPAD * SPAT;     // 2*128*S
    float* part  = f1 + (size_t)BATCH * 128 * SPAT;       // 2*224*1024*2
    float* stats = part + (size_t)BATCH * CPAD * 1024 * 2;// 32

    dim3 blk(256);
    dim3 gmm(SPAT / 128, 1, BATCH);                       // 512 blocks
    // cv1 + BN + ReLU : 64 -> 32 (MFMA)
    k_mfma_pw<64, 32, 32, true, true, false, false><<<gmm, blk, 0, stream>>>(
        x, w1, s1, b1, nullptr, a1, nullptr);
    // dw 5^3 + BN
    k_dw5<<<dim3(8, 32, BATCH), blk, 0, stream>>>(a1, w2, s2, b2, a2);
    // cv3 + BN + ReLU : 32 -> 32 (MFMA)
    k_mfma_pw<32, 32, 32, true, true, false, false><<<gmm, blk, 0, stream>>>(
        a2, w3, s3, b3, nullptr, a1, nullptr);
    // cv4 + bias : 32 -> 216(pad 224) (MFMA, fused GN partials)
    k_mfma_pw<32, CPAD, 216, false, false, true, false><<<gmm, blk, 0, stream>>>(
        a1, w4, nullptr, b4, nullptr, wkb, part);
    // GN stats stage 2
    k_gn_stats2<<<dim3(16), blk, 0, stream>>>(part, stats);
    // SKA + BN + residual -> y
    k_ska<<<dim3(SPAT / 1024, 8, BATCH), blk, 0, stream>>>(
        x, wkb, stats, gn_g, gn_b, bn_s, bn_b, yb);
    // pw1 + BN + ReLU : 64 -> 128 (MFMA)
    k_mfma_pw<64, 128, 128, true, true, false, false><<<gmm, blk, 0, stream>>>(
        yb, pw1_w, pw1_s, pw1_b, nullptr, f1, nullptr);
    // pw2 + BN + residual -> out : 128 -> 64 (MFMA)
    k_mfma_pw<128, 64, 64, false, true, false, true><<<gmm, blk, 0, stream>>>(
        f1, pw2_w, pw2_s, pw2_b, yb, (float*)d_out, nullptr);
}